// Round 10
// baseline (2130.137 us; speedup 1.0000x reference)
//
#include <hip/hip_runtime.h>
#include <math.h>
#include <stdint.h>

#define N_NODES 50000
#define N_EDGES 400000
#define N_T 4
#define N_R 8
#define N_H 8
#define DKD 32
#define D 256
#define TM 64
#define N_SEG (N_NODES * N_R)
#define PROJ_BLOCKS ((N_NODES + TM - 1) / TM + N_T)   // 786 >= sum of per-type ceils

typedef _Float16 h2 __attribute__((ext_vector_type(2)));
typedef _Float16 v8h __attribute__((ext_vector_type(8)));
typedef float v4f __attribute__((ext_vector_type(4)));
typedef unsigned short u16;

__device__ __forceinline__ u16 h2u(_Float16 h) { return __builtin_bit_cast(u16, h); }
__device__ __forceinline__ h2 u2h2(unsigned int u) { return __builtin_bit_cast(h2, u); }

// dot2 of f16 pairs with f32 accumulate: v_dot2_f32_f16 (1 instr = 2 MAC)
#if __has_builtin(__builtin_amdgcn_fdot2)
__device__ __forceinline__ float fdot2f(h2 a, h2 b, float c) {
    return __builtin_amdgcn_fdot2(a, b, c, false);
}
#else
__device__ __forceinline__ float fdot2f(h2 a, h2 b, float c) {
    return c + (float)a[0] * (float)b[0] + (float)a[1] * (float)b[1];
}
#endif

__device__ __forceinline__ unsigned int pk16(float a, float b) {
#if __has_builtin(__builtin_amdgcn_cvt_pkrtz)
    return __builtin_bit_cast(unsigned int, __builtin_amdgcn_cvt_pkrtz(a, b));
#else
    return __builtin_bit_cast(unsigned int, h2{(_Float16)a, (_Float16)b});
#endif
}

// 32-element f16 dot (rows as 4x uint4 = 64B): 16 fdot2
__device__ __forceinline__ float dot32h(const uint4* __restrict__ a,
                                        const uint4* __restrict__ q) {
    float s = 0.f;
    #pragma unroll
    for (int j = 0; j < 4; j++) {
        uint4 av = a[j], qv = q[j];
        s = fdot2f(u2h2(av.x), u2h2(qv.x), s);
        s = fdot2f(u2h2(av.y), u2h2(qv.y), s);
        s = fdot2f(u2h2(av.z), u2h2(qv.z), s);
        s = fdot2f(u2h2(av.w), u2h2(qv.w), s);
    }
    return s;
}

// ---------------- f32 -> f16 weight conversions ----------------
__global__ __launch_bounds__(256) void k_cvtW(
    const float4* __restrict__ w0, const float4* __restrict__ w1,
    const float4* __restrict__ w2, const float4* __restrict__ w3,
    ushort4* __restrict__ d, int n4each) {
    int i = blockIdx.x * 256 + threadIdx.x;
    if (i >= 4 * n4each) return;
    int sel = i / n4each, j = i - sel * n4each;
    const float4* s = (sel == 0) ? w0 : (sel == 1) ? w1 : (sel == 2) ? w2 : w3;
    float4 v = s[j];
    ushort4 o;
    o.x = h2u((_Float16)v.x); o.y = h2u((_Float16)v.y);
    o.z = h2u((_Float16)v.z); o.w = h2u((_Float16)v.w);
    d[i] = o;
}

// rel_att scaled by pri[r][h]/sqrt(dk)*log2(e) folded in (softmax via exp2)
__global__ __launch_bounds__(256) void k_cvt_att(const float4* __restrict__ s,
                                                 const float* __restrict__ pri,
                                                 ushort4* __restrict__ d, int n4) {
    int i = blockIdx.x * 256 + threadIdx.x;
    if (i >= n4) return;
    int mat = i >> 8;                         // 1024 elems = 256 float4 per matrix
    float sc = pri[mat] * 0.2550309305920868f;   // (1/sqrt(32)) * log2(e)
    float4 v = s[i];
    ushort4 o;
    o.x = h2u((_Float16)(v.x * sc)); o.y = h2u((_Float16)(v.y * sc));
    o.z = h2u((_Float16)(v.z * sc)); o.w = h2u((_Float16)(v.w * sc));
    d[i] = o;
}

// rel_msg [mat][d0][f] f32 -> Mt [mat][f][d0] f16 (per 32x32 matrix transpose)
__global__ __launch_bounds__(256) void k_cvt_t(const float* __restrict__ s,
                                               u16* __restrict__ d) {
    int i = blockIdx.x * 256 + threadIdx.x;
    if (i >= N_R * N_H * DKD * DKD) return;
    int mat = i >> 10, w = i & 1023;
    int d0 = w >> 5, f = w & 31;
    d[(mat << 10) + f * DKD + d0] = h2u((_Float16)s[i]);
}

// ---------------- bucketing by node type ----------------
__global__ void k_hist(const int* __restrict__ nt, int* __restrict__ cnt) {
    int n = blockIdx.x * blockDim.x + threadIdx.x;
    if (n < N_NODES) atomicAdd(&cnt[nt[n]], 1);
}

__global__ void k_scan(const int* __restrict__ cnt, int* __restrict__ off,
                       int* __restrict__ toff) {
    int o = 0, to = 0;
    for (int t = 0; t < N_T; t++) {
        off[t] = o; toff[t] = to;
        o += cnt[t]; to += (cnt[t] + TM - 1) / TM;
    }
    off[N_T] = o; toff[N_T] = to;
}

__global__ void k_scatter(const int* __restrict__ nt, const int* __restrict__ off,
                          int* __restrict__ cur, int* __restrict__ order) {
    int n = blockIdx.x * blockDim.x + threadIdx.x;
    if (n >= N_NODES) return;
    int t = nt[n];
    int pos = off[t] + atomicAdd(&cur[t], 1);
    order[pos] = n;
}

// ---------------- segment CSR (seg = dst*R + etype) ----------------
__global__ void k_hist_seg(const int* __restrict__ dst, const int* __restrict__ et,
                           int* __restrict__ cnt) {
    int e = blockIdx.x * blockDim.x + threadIdx.x;
    if (e < N_EDGES) atomicAdd(&cnt[dst[e] * N_R + et[e]], 1);
}

__global__ __launch_bounds__(1024) void k_scan_l1(const int* __restrict__ cnt,
                                                  int* __restrict__ excl,
                                                  int* __restrict__ bsum) {
    __shared__ int sh[1024];
    int tid = threadIdx.x, i = blockIdx.x * 1024 + tid;
    int v = (i < N_SEG) ? cnt[i] : 0;
    sh[tid] = v;
    __syncthreads();
    #pragma unroll
    for (int ofs = 1; ofs < 1024; ofs <<= 1) {
        int t = (tid >= ofs) ? sh[tid - ofs] : 0;
        __syncthreads();
        sh[tid] += t;
        __syncthreads();
    }
    if (i < N_SEG) excl[i] = sh[tid] - v;
    if (tid == 1023) bsum[blockIdx.x] = sh[1023];
}

__global__ __launch_bounds__(512) void k_scan_l2(int* __restrict__ bsum, int NB) {
    __shared__ int sh[512];
    int tid = threadIdx.x;
    int v = (tid < NB) ? bsum[tid] : 0;
    sh[tid] = v;
    __syncthreads();
    #pragma unroll
    for (int ofs = 1; ofs < 512; ofs <<= 1) {
        int t = (tid >= ofs) ? sh[tid - ofs] : 0;
        __syncthreads();
        sh[tid] += t;
        __syncthreads();
    }
    if (tid < NB) bsum[tid] = sh[tid] - v;
}

__global__ void k_scan_l3(int* __restrict__ excl, const int* __restrict__ bsum) {
    int i = blockIdx.x * blockDim.x + threadIdx.x;
    if (i < N_SEG) excl[i] += bsum[i >> 10];
    else if (i == N_SEG) excl[N_SEG] = N_EDGES;
}

// scatter src node id (u16) per segment slot — stream lives in ws
__global__ void k_scatter_seg(const int* __restrict__ src, const int* __restrict__ dst,
                              const int* __restrict__ et, const int* __restrict__ rp,
                              int* __restrict__ cur, u16* __restrict__ esrc16) {
    int e = blockIdx.x * blockDim.x + threadIdx.x;
    if (e >= N_EDGES) return;
    int sg = dst[e] * N_R + et[e];
    int pos = rp[sg] + atomicAdd(&cur[sg], 1);
    esrc16[pos] = (u16)src[e];
}

// ---------------- fused typed K/Q/V projection (MFMA, f16) ----------------
__global__ __launch_bounds__(256) void k_proj(
    const float* __restrict__ x, const int* __restrict__ order,
    const int* __restrict__ off, const int* __restrict__ toff,
    const u16* __restrict__ Wkb, const float* __restrict__ bk,
    const u16* __restrict__ Wqb, const float* __restrict__ bq,
    const u16* __restrict__ Wvb, const float* __restrict__ bv,
    u16* __restrict__ Kb, u16* __restrict__ Qb, u16* __restrict__ Vb) {
    __shared__ __align__(16) u16 xs[TM][D + 8];
    int b = blockIdx.x;
    int t = -1;
    #pragma unroll
    for (int i = 0; i < N_T; i++)
        if (b >= toff[i] && b < toff[i + 1]) t = i;
    if (t < 0) return;
    int nodeBase = off[t] + (b - toff[t]) * TM;
    int count = min(TM, off[t + 1] - nodeBase);
    int tid = threadIdx.x;

    for (int j = tid; j < TM * (D / 4); j += 256) {
        int row = j >> 6, ch = j & 63;
        float4 v = {0.f, 0.f, 0.f, 0.f};
        if (row < count) {
            int g = order[nodeBase + row];
            v = *(const float4*)(x + (size_t)g * D + ch * 4);
        }
        ushort4 o;
        o.x = h2u((_Float16)v.x); o.y = h2u((_Float16)v.y);
        o.z = h2u((_Float16)v.z); o.w = h2u((_Float16)v.w);
        *(ushort4*)&xs[row][ch * 4] = o;
    }
    __syncthreads();

    int lane = tid & 63, wave = tid >> 6;
    int m = lane & 15, quad = lane >> 4;
    v8h a[8];
    #pragma unroll
    for (int ks = 0; ks < 8; ks++)
        a[ks] = *(const v8h*)&xs[wave * 16 + m][ks * 32 + quad * 8];

    int grow[4]; bool vrow[4];
    #pragma unroll
    for (int r = 0; r < 4; r++) {
        int rowi = wave * 16 + quad * 4 + r;
        vrow[r] = (rowi < count);
        grow[r] = vrow[r] ? order[nodeBase + rowi] : 0;
    }

    const u16* Ws[3] = {Wkb + (size_t)t * D * D, Wqb + (size_t)t * D * D, Wvb + (size_t)t * D * D};
    const float* Bs[3] = {bk + t * D, bq + t * D, bv + t * D};
    u16* Os[3] = {Kb, Qb, Vb};

    for (int p = 0; p < 3; p++) {
        const u16* W = Ws[p];
        for (int dt = 0; dt < 16; dt++) {
            int dcol = dt * 16 + m;
            v4f acc = {0.f, 0.f, 0.f, 0.f};
            #pragma unroll
            for (int ks = 0; ks < 8; ks++) {
                v8h bf = *(const v8h*)(W + (size_t)dcol * D + ks * 32 + quad * 8);
                acc = __builtin_amdgcn_mfma_f32_16x16x32_f16(a[ks], bf, acc, 0, 0, 0);
            }
            float bias = Bs[p][dcol];
            #pragma unroll
            for (int r = 0; r < 4; r++) {
                if (vrow[r])
                    Os[p][(size_t)grow[r] * D + dcol] = h2u((_Float16)(acc[r] + bias));
            }
        }
    }
}

// ---------------- fused attention: ONE WAVE PER (node, relation) ------------
// Block = node (512 threads = 8 waves); wave w handles relation r=w.
// Lane = h*8+fl owns head h, feature slice [fl*4, fl*4+4).
// All r-indexing is compile-time static (r = wave id): no switches, single
// den/ua accumulators, no mixed-r machinery. Absent-r waves exit to barrier.
// Cross-r mean via LDS block reduce; one 512B f16 store per node.
__global__ __launch_bounds__(512) void k_fused(
    const u16* __restrict__ Kb, u16* QTb, const u16* __restrict__ Vb,
    const int* __restrict__ rowptr_seg, const u16* __restrict__ esrc16,
    const u16* __restrict__ Ab, const u16* __restrict__ Mtb) {
    __shared__ __align__(16) unsigned int Uex[N_R][N_H][20];   // 5.1 KB
    __shared__ __align__(16) float msh[N_R][64][4];            // 8 KB
    __shared__ int flg[N_R];
    int tid = threadIdx.x;
    int w = tid >> 6, lane = tid & 63;
    int n = blockIdx.x;
    int h = lane >> 3, fl = lane & 7, fo = fl * 4;

    int s0 = __builtin_amdgcn_readfirstlane(rowptr_seg[n * N_R + w]);
    int s1 = __builtin_amdgcn_readfirstlane(rowptr_seg[n * N_R + w + 1]);
    if (lane == 0) flg[w] = (s0 < s1) ? 1 : 0;

    float macc[4] = {0.f, 0.f, 0.f, 0.f};
    if (s0 < s1) {                             // wave-uniform (scalar bounds)
        // own-head Q slice (64B; 8 fl-lanes share the line)
        uint4 qv4[4];
        {
            const uint4* qp = (const uint4*)(QTb + (size_t)n * D + h * DKD);
            qv4[0] = qp[0]; qv4[1] = qp[1]; qv4[2] = qp[2]; qv4[3] = qp[3];
        }
        // qtilde rows fo..fo+3 of head h, relation w (scale pre-folded in Ab)
        const u16* Ar = Ab + ((size_t)(w * N_H + h) * DKD + fo) * DKD;
        float q0 = dot32h((const uint4*)(Ar), qv4);
        float q1 = dot32h((const uint4*)(Ar + DKD), qv4);
        float q2 = dot32h((const uint4*)(Ar + 2 * DKD), qv4);
        float q3 = dot32h((const uint4*)(Ar + 3 * DKD), qv4);
        h2 qta = h2{(_Float16)q0, (_Float16)q1};
        h2 qtb = h2{(_Float16)q2, (_Float16)q3};

        // edge loop over this segment (avg 1.6 edges)
        float den = 0.f, ua0 = 0.f, ua1 = 0.f, ua2 = 0.f, ua3 = 0.f;
        size_t hoff = (size_t)(h * DKD + fo);
        for (int e = s0; e < s1; e++) {
            int s = __builtin_amdgcn_readfirstlane((int)esrc16[e]);
            uint2 ku = *(const uint2*)(Kb + (size_t)s * D + hoff);
            uint2 vu = *(const uint2*)(Vb + (size_t)s * D + hoff);
            float p = fdot2f(u2h2(ku.y), qtb, fdot2f(u2h2(ku.x), qta, 0.f));
            p += __shfl_xor(p, 1);
            p += __shfl_xor(p, 2);
            p += __shfl_xor(p, 4);             // full 32-dot in all 8 fl-lanes
            float ex = exp2f(p);               // log2e folded into Ab
            den += ex;
            h2 va = u2h2(vu.x), vb = u2h2(vu.y);
            ua0 += ex * (float)va[0]; ua1 += ex * (float)va[1];
            ua2 += ex * (float)vb[0]; ua3 += ex * (float)vb[1];
        }

        // normalize, exchange U within wave, M-transform (static r = w)
        float invd = 1.f / den;
        unsigned int pw0 = pk16(ua0 * invd, ua1 * invd);
        unsigned int pw1 = pk16(ua2 * invd, ua3 * invd);
        __builtin_amdgcn_wave_barrier();
        *(uint2*)&Uex[w][h][fl * 2] = uint2{pw0, pw1};
        __builtin_amdgcn_wave_barrier();
        uint4 Um[4];
        #pragma unroll
        for (int j = 0; j < 4; j++)
            Um[j] = *(const uint4*)&Uex[w][h][4 * j];
        const u16* mp = Mtb + ((size_t)(w * N_H + h) * DKD + fo) * DKD;
        #pragma unroll
        for (int j = 0; j < 4; j++)
            macc[j] += dot32h((const uint4*)(mp + j * DKD), Um);
    }

    *(float4*)&msh[w][lane][0] = {macc[0], macc[1], macc[2], macc[3]};
    __syncthreads();

    if (tid < 64) {
        float4 sum = {0.f, 0.f, 0.f, 0.f};
        int np = 0;
        #pragma unroll
        for (int ww = 0; ww < N_R; ww++) {
            np += flg[ww];
            float4 m = *(const float4*)&msh[ww][tid][0];
            sum.x += m.x; sum.y += m.y; sum.z += m.z; sum.w += m.w;
        }
        float invp = (np > 0) ? 1.f / (float)np : 1.f;
        unsigned int o0 = pk16(sum.x * invp, sum.y * invp);
        unsigned int o1 = pk16(sum.z * invp, sum.w * invp);
        int hh = tid >> 3, ff = tid & 7;
        *(uint2*)(QTb + (size_t)n * D + hh * DKD + ff * 4) = uint2{o0, o1};
    }
}

// ---------------- typed output linear + sigmoid-skip blend (MFMA, f16) ----------------
__global__ __launch_bounds__(256) void k_out(
    const u16* __restrict__ TBF, const float* __restrict__ x,
    const int* __restrict__ order, const int* __restrict__ off, const int* __restrict__ toff,
    const u16* __restrict__ Wab, const float* __restrict__ ba,
    const float* __restrict__ skip, float* __restrict__ out) {
    __shared__ __align__(16) u16 xs[TM][D + 8];
    int b = blockIdx.x;
    int t = -1;
    #pragma unroll
    for (int i = 0; i < N_T; i++)
        if (b >= toff[i] && b < toff[i + 1]) t = i;
    if (t < 0) return;
    int nodeBase = off[t] + (b - toff[t]) * TM;
    int count = min(TM, off[t + 1] - nodeBase);
    int tid = threadIdx.x;

    for (int j = tid; j < TM * 32; j += 256) {
        int row = j >> 5, ch = j & 31;
        ushort4 z = {0, 0, 0, 0};
        if (row < count) {
            int g = order[nodeBase + row];
            const ushort4* p = (const ushort4*)(TBF + (size_t)g * D + ch * 8);
            *(ushort4*)&xs[row][ch * 8] = p[0];
            *(ushort4*)&xs[row][ch * 8 + 4] = p[1];
        } else {
            *(ushort4*)&xs[row][ch * 8] = z;
            *(ushort4*)&xs[row][ch * 8 + 4] = z;
        }
    }
    __syncthreads();

    int lane = tid & 63, wave = tid >> 6;
    int m = lane & 15, quad = lane >> 4;
    v8h a[8];
    #pragma unroll
    for (int ks = 0; ks < 8; ks++)
        a[ks] = *(const v8h*)&xs[wave * 16 + m][ks * 32 + quad * 8];

    int grow[4]; bool vrow[4];
    #pragma unroll
    for (int r = 0; r < 4; r++) {
        int rowi = wave * 16 + quad * 4 + r;
        vrow[r] = (rowi < count);
        grow[r] = vrow[r] ? order[nodeBase + rowi] : 0;
    }

    float sv = skip[t];
    float alpha = 1.f / (1.f + __expf(-sv));
    float beta = 1.f - alpha;
    const u16* W = Wab + (size_t)t * D * D;

    for (int dt = 0; dt < 16; dt++) {
        int dcol = dt * 16 + m;
        v4f acc = {0.f, 0.f, 0.f, 0.f};
        #pragma unroll
        for (int ks = 0; ks < 8; ks++) {
            v8h bf = *(const v8h*)(W + (size_t)dcol * D + ks * 32 + quad * 8);
            acc = __builtin_amdgcn_mfma_f32_16x16x32_f16(a[ks], bf, acc, 0, 0, 0);
        }
        float bias = ba[t * D + dcol];
        #pragma unroll
        for (int r = 0; r < 4; r++) {
            if (vrow[r]) {
                size_t o = (size_t)grow[r] * D + dcol;
                out[o] = alpha * (acc[r] + bias) + beta * x[o];
            }
        }
    }
}

// ---------------- launch ----------------
extern "C" void kernel_launch(void* const* d_in, const int* in_sizes, int n_in,
                              void* d_out, int out_size, void* d_ws, size_t ws_size,
                              hipStream_t stream) {
    const float* x       = (const float*)d_in[0];
    const int* node_type = (const int*)d_in[1];
    const int* src       = (const int*)d_in[2];
    const int* dst       = (const int*)d_in[3];
    const int* etype     = (const int*)d_in[4];
    const float* Wk = (const float*)d_in[5];
    const float* bk = (const float*)d_in[6];
    const float* Wq = (const float*)d_in[7];
    const float* bq = (const float*)d_in[8];
    const float* Wv = (const float*)d_in[9];
    const float* bv = (const float*)d_in[10];
    const float* Wa = (const float*)d_in[11];
    const float* ba = (const float*)d_in[12];
    const float* rel_pri = (const float*)d_in[13];
    const float* rel_att = (const float*)d_in[14];
    const float* rel_msg = (const float*)d_in[15];
    const float* skip    = (const float*)d_in[16];
    float* out = (float*)d_out;
    char* ws = (char*)d_ws;

    const size_t SZH = (size_t)N_NODES * D * 2;          // 25.6 MB
    const size_t WSZ = (size_t)N_T * D * D;              // 262144 elems
    const size_t RSZ = (size_t)N_R * N_H * DKD * DKD;    // 65536 elems
    u16* Kb  = (u16*)(ws);
    u16* Qb  = (u16*)(ws + SZH);
    u16* Vb  = (u16*)(ws + 2 * SZH);
    u16* TBF = Qb;                              // aliases Qb
    u16* Wkb = (u16*)(ws + 3 * SZH);
    u16* Wqb = Wkb + WSZ;
    u16* Wvb = Wqb + WSZ;
    u16* Wab = Wvb + WSZ;
    u16* Ab  = Wab + WSZ;
    u16* Mtb = Ab + RSZ;
    int* order = (int*)(Mtb + RSZ);
    int* small = order + N_NODES;
    int* cnt  = small;        // 4
    int* cur  = small + 4;    // 4
    int* offp = small + 8;    // 5
    int* toffp= small + 13;   // 5

    // edge stream aliases Wkb region (written only after k_proj completes)
    u16* esrc16 = Wkb;                                   // 800 KB (fits 1.57 MB)

    // d_out as scratch: segment-CSR build (all dead before k_out rewrites it)
    char* ob = (char*)d_out;
    int* rowptr_seg = (int*)ob;                          // 400001
    int* cnt_seg    = rowptr_seg + (N_SEG + 16);         // 400000
    int* cur_seg    = cnt_seg + N_SEG;                   // 400000 (contiguous)
    int* bsum       = cur_seg + N_SEG;                   // 391 (+pad)

    hipMemsetAsync(small, 0, 8 * sizeof(int), stream);
    hipMemsetAsync(cnt_seg, 0, 2 * (size_t)N_SEG * sizeof(int), stream);

    // weight conversions (f32 -> f16)
    k_cvtW<<<(4 * (WSZ / 4) + 255) / 256, 256, 0, stream>>>(
        (const float4*)Wk, (const float4*)Wq, (const float4*)Wv, (const float4*)Wa,
        (ushort4*)Wkb, WSZ / 4);
    k_cvt_att<<<(RSZ / 4 + 255) / 256, 256, 0, stream>>>(
        (const float4*)rel_att, rel_pri, (ushort4*)Ab, RSZ / 4);
    k_cvt_t<<<(RSZ + 255) / 256, 256, 0, stream>>>(rel_msg, Mtb);

    // node-type buckets
    k_hist<<<(N_NODES + 255) / 256, 256, 0, stream>>>(node_type, cnt);
    k_scan<<<1, 1, 0, stream>>>(cnt, offp, toffp);
    k_scatter<<<(N_NODES + 255) / 256, 256, 0, stream>>>(node_type, offp, cur, order);

    // projections FIRST (weights die here; their space becomes the edge stream)
    k_proj<<<PROJ_BLOCKS, 256, 0, stream>>>(x, order, offp, toffp,
                                            Wkb, bk, Wqb, bq, Wvb, bv, Kb, Qb, Vb);

    // segment CSR build (scratch + rowptr in d_out; esrc16 in ws)
    const int NB = (N_SEG + 1023) / 1024;                // 391
    k_hist_seg<<<(N_EDGES + 255) / 256, 256, 0, stream>>>(dst, etype, cnt_seg);
    k_scan_l1<<<NB, 1024, 0, stream>>>(cnt_seg, rowptr_seg, bsum);
    k_scan_l2<<<1, 512, 0, stream>>>(bsum, NB);
    k_scan_l3<<<(N_SEG + 1 + 255) / 256, 256, 0, stream>>>(rowptr_seg, bsum);
    k_scatter_seg<<<(N_EDGES + 255) / 256, 256, 0, stream>>>(src, dst, etype,
                                                             rowptr_seg, cur_seg,
                                                             esrc16);

    k_fused<<<N_NODES, 512, 0, stream>>>(Kb, Qb, Vb, rowptr_seg, esrc16, Ab, Mtb);

    k_out<<<PROJ_BLOCKS, 256, 0, stream>>>(TBF, x, order, offp, toffp,
                                           Wab, ba, skip, out);
}